// Round 11
// baseline (327.742 us; speedup 1.0000x reference)
//
#include <hip/hip_runtime.h>
#include <math.h>

#define N_NODES 50000
#define N_EDGES 600000
#define D 128
#define BN_EPS 1e-5f
#define ELLW 64

typedef float f32x4 __attribute__((ext_vector_type(4)));
typedef short short8 __attribute__((ext_vector_type(8)));

__device__ __forceinline__ unsigned short f2bf(float f) {
    unsigned int x = __float_as_uint(f);
    return (unsigned short)((x + 0x7FFFu + ((x >> 16) & 1u)) >> 16);  // RNE
}

// ---------------- prep: transpose+bf16 weights, zero cur + stats ----------------
__global__ void prep_kernel(const float* __restrict__ W1, const float* __restrict__ W2,
                            unsigned short* __restrict__ WT1, unsigned short* __restrict__ WT2,
                            int* __restrict__ cur, float* __restrict__ stats) {
    int idx = blockIdx.x * blockDim.x + threadIdx.x;
    if (idx < D * D) {
        int col = idx >> 7, k = idx & 127;
        WT1[col * D + k] = f2bf(W1[k * D + col]);
        WT2[col * D + k] = f2bf(W2[k * D + col]);
    }
    if (idx < N_NODES) cur[idx] = 0;
    if (idx < 4 * D) stats[idx] = 0.0f;
}

// ---------------- build ELL adjacency: dst -> list of src (int) ----------------
__global__ void scatter_kernel(const int* __restrict__ srcI, const int* __restrict__ dstI,
                               int* __restrict__ cur, int* __restrict__ ell) {
    int e = blockIdx.x * blockDim.x + threadIdx.x;
    if (e >= N_EDGES) return;
    int d = dstI[e];
    int pos = atomicAdd(&cur[d], 1);
    if (pos < ELLW) ell[(size_t)d * ELLW + pos] = srcI[e];
}

// ---------------- LDS-B MFMA GEMM ----------------
// B (128x128 bf16, 32KB) staged to LDS once per block with XOR-swizzled 16B granules:
//   granule g = row*16 + (k>>3) stored at g ^ (row&7)  -> quarter-wave ds_read_b128
//   across rows hits 8 distinct granule slots (2-way = free) instead of 16-way conflict.
// Low VGPR (~100) -> launch_bounds(256,4): 4 waves/SIMD, 4 blocks/CU (LDS 34.8KB).
// Grid-stride over 16-row tiles. OUT_BF16 writes C as bf16.
template<bool BN, bool HAS_BIAS, bool STATS, bool OUT_BF16>
__global__ __launch_bounds__(256, 4) void gemm_lds_kernel(
    const float* __restrict__ A, const unsigned short* __restrict__ WT,
    const float* __restrict__ bn_sum, const float* __restrict__ bn_sq,
    const float* __restrict__ bn_gamma, const float* __restrict__ bn_beta,
    const float* __restrict__ out_bias, float* __restrict__ C,
    unsigned short* __restrict__ Cb, int M,
    float* __restrict__ sum_out, float* __restrict__ sq_out)
{
    __shared__ unsigned short LB[D * D];      // 32 KB swizzled B
    __shared__ __align__(16) float scs[D];
    __shared__ __align__(16) float bis[D];
    __shared__ float ssum[D];
    __shared__ float ssq[D];

    const int tid  = threadIdx.x;
    const int lane = tid & 63;
    const int w    = tid >> 6;
    const int l15  = lane & 15;
    const int lg   = lane >> 4;
    const int x3   = l15 & 7;

    if (BN) {
        if (tid < D) {
            const float inv_n = 1.0f / (float)N_NODES;
            float mean = bn_sum[tid] * inv_n;
            float var  = bn_sq[tid] * inv_n - mean * mean;
            float rstd = rsqrtf(var + BN_EPS);
            float sc = bn_gamma[tid] * rstd;
            scs[tid] = sc;
            bis[tid] = bn_beta[tid] - mean * sc;
        }
    }
    if (STATS) {
        if (tid < D) { ssum[tid] = 0.f; ssq[tid] = 0.f; }
    }
    // stage B into LDS (swizzled granules); 2048 granules of 16B
    for (int g = tid; g < 2048; g += 256) {
        int row = g >> 4, c8 = g & 15;
        int gs = (row << 4) | (c8 ^ (row & 7));
        *(short8*)&LB[gs << 3] = *(const short8*)&WT[(size_t)g << 3];
    }
    __syncthreads();

    float ob[8];
    #pragma unroll
    for (int ct = 0; ct < 8; ++ct) ob[ct] = HAS_BIAS ? out_bias[ct * 16 + l15] : 0.f;

    float psum[8], psq[8];
    #pragma unroll
    for (int ct = 0; ct < 8; ++ct) { psum[ct] = 0.f; psq[ct] = 0.f; }

    const int nt = (M + 15) / 16;   // 3125 row tiles
    for (int t = blockIdx.x * 4 + w; t < nt; t += gridDim.x * 4) {
        int ar = t * 16 + l15; if (ar > M - 1) ar = M - 1;
        short8 af[4];
        #pragma unroll
        for (int ks = 0; ks < 4; ++ks) {
            const int kb = ks * 32 + lg * 8;
            const float* ap = &A[(size_t)ar * D + kb];
            float4 v0 = *(const float4*)ap;
            float4 v1 = *(const float4*)(ap + 4);
            float vv[8] = {v0.x, v0.y, v0.z, v0.w, v1.x, v1.y, v1.z, v1.w};
            short8 a8;
            #pragma unroll
            for (int j = 0; j < 8; ++j) {
                float f = vv[j];
                if (BN) f = fmaxf(fmaf(f, scs[kb + j], bis[kb + j]), 0.f);
                a8[j] = (short)f2bf(f);
            }
            af[ks] = a8;
        }

        f32x4 acc[8];
        #pragma unroll
        for (int ct = 0; ct < 8; ++ct) acc[ct] = (f32x4){0.f, 0.f, 0.f, 0.f};
        #pragma unroll
        for (int ks = 0; ks < 4; ++ks) {
            #pragma unroll
            for (int ct = 0; ct < 8; ++ct) {
                // granule: ct*256 + l15*16 + ((ks*4+lg) ^ x3)
                int gidx = (ct << 8) + (l15 << 4) + (((ks << 2) + lg) ^ x3);
                short8 bf = *(const short8*)&LB[gidx << 3];
                acc[ct] = __builtin_amdgcn_mfma_f32_16x16x32_bf16(af[ks], bf, acc[ct], 0, 0, 0);
            }
        }

        // C/D layout: col = ct*16 + l15, row = t*16 + lg*4 + j
        const int rb2 = t * 16 + lg * 4;
        #pragma unroll
        for (int j = 0; j < 4; ++j) {
            const int row = rb2 + j;
            if (row < M) {
                #pragma unroll
                for (int ct = 0; ct < 8; ++ct) {
                    float o = acc[ct][j] + ob[ct];
                    if (OUT_BF16) Cb[(size_t)row * D + ct * 16 + l15] = f2bf(o);
                    else          C[(size_t)row * D + ct * 16 + l15] = o;
                    if (STATS) { psum[ct] += o; psq[ct] = fmaf(o, o, psq[ct]); }
                }
            }
        }
    }

    if (STATS) {
        #pragma unroll
        for (int ct = 0; ct < 8; ++ct) {
            atomicAdd(&ssum[ct * 16 + l15], psum[ct]);
            atomicAdd(&ssq[ct * 16 + l15], psq[ct]);
        }
        __syncthreads();
        if (tid < D) {
            unsafeAtomicAdd(&sum_out[tid], ssum[tid]);
            unsafeAtomicAdd(&sq_out[tid], ssq[tid]);
        }
    }
}

// bf16-pair load helper: word -> two floats
__device__ __forceinline__ void bfp(unsigned pv, float& fx, float& fy) {
    fx = __uint_as_float(pv << 16);
    fy = __uint_as_float(pv & 0xFFFF0000u);
}

// ---------------- gather over bf16 h2: TWO nodes per wave, 4-edge unroll ----------------
// degree weights computed on the fly from cnt (no dinv array)
__global__ __launch_bounds__(256) void gather_kernel(
    const int* __restrict__ ell, const int* __restrict__ cnt,
    const unsigned short* __restrict__ h2b,
    const float* __restrict__ b_conv, float* __restrict__ outpre,
    float* __restrict__ sum_out, float* __restrict__ sq_out)
{
    const int lane = threadIdx.x & 63;
    const int wid  = threadIdx.x >> 6;
    const int col  = lane * 2;
    const float2 bc = *(const float2*)&b_conv[col];
    float2 sum = make_float2(0.f, 0.f);
    float2 sq  = make_float2(0.f, 0.f);

    for (int d0 = blockIdx.x * 8 + wid * 2; d0 < N_NODES; d0 += gridDim.x * 8) {
        const int d1 = d0 + 1;
        int cAr = cnt[d0];
        int cBr = cnt[d1];
        const float ddA = rsqrtf((float)cAr + 1.0f);
        const float ddB = rsqrtf((float)cBr + 1.0f);
        int cA = cAr > ELLW ? ELLW : cAr;
        int cB = cBr > ELLW ? ELLW : cBr;
        float hAx, hAy, hBx, hBy;
        bfp(*(const unsigned*)&h2b[(size_t)d0 * D + col], hAx, hAy);
        bfp(*(const unsigned*)&h2b[(size_t)d1 * D + col], hBx, hBy);
        float2 accA, accB;
        accA.x = ddA * hAx; accA.y = ddA * hAy;
        accB.x = ddB * hBx; accB.y = ddB * hBy;

        int slA = 0, slB = 0;
        float wlA = 0.f, wlB = 0.f;
        if (lane < cA) { slA = ell[(size_t)d0 * ELLW + lane]; wlA = rsqrtf((float)cnt[slA] + 1.0f); }
        if (lane < cB) { slB = ell[(size_t)d1 * ELLW + lane]; wlB = rsqrtf((float)cnt[slB] + 1.0f); }

        const int cmin = cA < cB ? cA : cB;
        int j = 0;
        for (; j + 4 <= cmin; j += 4) {
            unsigned pA[4], pB[4];
            float wA[4], wB[4];
            #pragma unroll
            for (int u = 0; u < 4; ++u) {
                int sA = __shfl(slA, j + u);
                int sB = __shfl(slB, j + u);
                wA[u] = __shfl(wlA, j + u);
                wB[u] = __shfl(wlB, j + u);
                pA[u] = *(const unsigned*)&h2b[(size_t)sA * D + col];
                pB[u] = *(const unsigned*)&h2b[(size_t)sB * D + col];
            }
            #pragma unroll
            for (int u = 0; u < 4; ++u) {
                float ax, ay, bx, by;
                bfp(pA[u], ax, ay);
                bfp(pB[u], bx, by);
                accA.x = fmaf(wA[u], ax, accA.x);
                accA.y = fmaf(wA[u], ay, accA.y);
                accB.x = fmaf(wB[u], bx, accB.x);
                accB.y = fmaf(wB[u], by, accB.y);
            }
        }
        int jA = j, jB = j;
        for (; jA < cA; ++jA) {
            int s = __shfl(slA, jA);
            float ww = __shfl(wlA, jA);
            float ax, ay;
            bfp(*(const unsigned*)&h2b[(size_t)s * D + col], ax, ay);
            accA.x = fmaf(ww, ax, accA.x);
            accA.y = fmaf(ww, ay, accA.y);
        }
        for (; jB < cB; ++jB) {
            int s = __shfl(slB, jB);
            float ww = __shfl(wlB, jB);
            float bx, by;
            bfp(*(const unsigned*)&h2b[(size_t)s * D + col], bx, by);
            accB.x = fmaf(ww, bx, accB.x);
            accB.y = fmaf(ww, by, accB.y);
        }

        float2 oA, oB;
        oA.x = fmaf(ddA, accA.x, bc.x);
        oA.y = fmaf(ddA, accA.y, bc.y);
        oB.x = fmaf(ddB, accB.x, bc.x);
        oB.y = fmaf(ddB, accB.y, bc.y);
        *(float2*)&outpre[(size_t)d0 * D + col] = oA;
        *(float2*)&outpre[(size_t)d1 * D + col] = oB;
        sum.x += oA.x + oB.x; sum.y += oA.y + oB.y;
        sq.x = fmaf(oA.x, oA.x, sq.x); sq.x = fmaf(oB.x, oB.x, sq.x);
        sq.y = fmaf(oA.y, oA.y, sq.y); sq.y = fmaf(oB.y, oB.y, sq.y);
    }

    __shared__ float2 sS[256];
    __shared__ float2 qS[256];
    sS[threadIdx.x] = sum; qS[threadIdx.x] = sq;
    __syncthreads();
    if (wid == 0) {
        #pragma unroll
        for (int w = 1; w < 4; ++w) {
            float2 s2 = sS[w * 64 + lane];
            float2 q2 = qS[w * 64 + lane];
            sum.x += s2.x; sum.y += s2.y;
            sq.x += q2.x; sq.y += q2.y;
        }
        unsafeAtomicAdd(&sum_out[col + 0], sum.x);
        unsafeAtomicAdd(&sum_out[col + 1], sum.y);
        unsafeAtomicAdd(&sq_out[col + 0], sq.x);
        unsafeAtomicAdd(&sq_out[col + 1], sq.y);
    }
}

// ---------------- final: out = relu(out*scale2 + bias2), scale/bias from raw stats ----------------
__global__ void final_kernel(float* __restrict__ out,
        const float* __restrict__ s_sum, const float* __restrict__ s_sq,
        const float* __restrict__ gamma, const float* __restrict__ beta) {
    __shared__ __align__(16) float scs[D];
    __shared__ __align__(16) float bis[D];
    const int tid = threadIdx.x;
    if (tid < D) {
        const float inv_n = 1.0f / (float)N_NODES;
        float mean = s_sum[tid] * inv_n;
        float var  = s_sq[tid] * inv_n - mean * mean;
        float rstd = rsqrtf(var + BN_EPS);
        float sc = gamma[tid] * rstd;
        scs[tid] = sc;
        bis[tid] = beta[tid] - mean * sc;
    }
    __syncthreads();
    const int t = blockIdx.x * blockDim.x + tid;
    const int c4 = t & 31;
    float4 sc = *(const float4*)&scs[c4 * 4];
    float4 bi = *(const float4*)&bis[c4 * 4];
    const int total = N_NODES * D / 4;
    const int stride = gridDim.x * blockDim.x;
    for (int i = t; i < total; i += stride) {
        float4 v = ((const float4*)out)[i];
        v.x = fmaxf(fmaf(v.x, sc.x, bi.x), 0.f);
        v.y = fmaxf(fmaf(v.y, sc.y, bi.y), 0.f);
        v.z = fmaxf(fmaf(v.z, sc.z, bi.z), 0.f);
        v.w = fmaxf(fmaf(v.w, sc.w, bi.w), 0.f);
        ((float4*)out)[i] = v;
    }
}

extern "C" void kernel_launch(void* const* d_in, const int* in_sizes, int n_in,
                              void* d_out, int out_size, void* d_ws, size_t ws_size,
                              hipStream_t stream) {
    const float* x      = (const float*)d_in[0];
    const int*   edge   = (const int*)d_in[1];      // [2][N_EDGES], row0=src, row1=dst
    const float* W_mlp  = (const float*)d_in[2];
    const float* b_mlp  = (const float*)d_in[3];
    const float* gamma1 = (const float*)d_in[4];
    const float* beta1  = (const float*)d_in[5];
    const float* W_conv = (const float*)d_in[6];
    const float* b_conv = (const float*)d_in[7];
    const float* gamma2 = (const float*)d_in[8];
    const float* beta2  = (const float*)d_in[9];
    float* out = (float*)d_out;

    float* ws = (float*)d_ws;
    float* h1   = ws;                                  // N*D floats (25.6 MB)
    unsigned short* h2b = (unsigned short*)(ws + (size_t)N_NODES * D);  // N*D bf16 (12.8 MB)
    int*   ell  = (int*)h1;                            // alias: h1 dead after gemm2 (12.8MB)
    float* extra = ws + 2 * (size_t)N_NODES * D;
    int*   cur  = (int*)extra;                         // N ints (ELL cursors / in-degree)
    float* stats = extra + N_NODES;                    // 4*D
    float* sum1 = stats;         float* sq1 = stats + D;
    float* sum2 = stats + 2 * D; float* sq2 = stats + 3 * D;
    unsigned short* WT1 = (unsigned short*)(stats + 4 * D);   // 128*128 bf16
    unsigned short* WT2 = WT1 + D * D;

    const int* srcI = edge;
    const int* dstI = edge + N_EDGES;

    prep_kernel<<<(N_NODES + 255) / 256, 256, 0, stream>>>(W_mlp, W_conv, WT1, WT2, cur, stats);

    gemm_lds_kernel<false, true, true, false><<<1024, 256, 0, stream>>>(
        x, WT1, nullptr, nullptr, nullptr, nullptr, b_mlp, h1, nullptr, N_NODES, sum1, sq1);

    gemm_lds_kernel<true, false, false, true><<<1024, 256, 0, stream>>>(
        h1, WT2, sum1, sq1, gamma1, beta1, nullptr, nullptr, h2b, N_NODES, nullptr, nullptr);

    // h1 is dead now: build src ELL in its place
    scatter_kernel<<<(N_EDGES + 255) / 256, 256, 0, stream>>>(srcI, dstI, cur, ell);

    gather_kernel<<<1024, 256, 0, stream>>>(ell, cur, h2b, b_conv, out, sum2, sq2);

    final_kernel<<<2048, 256, 0, stream>>>(out, sum2, sq2, gamma2, beta2);
}

// Round 12
// 297.624 us; speedup vs baseline: 1.1012x; 1.1012x over previous
//
#include <hip/hip_runtime.h>
#include <math.h>

#define N_NODES 50000
#define N_EDGES 600000
#define D 128
#define BN_EPS 1e-5f
#define ELLW 64

typedef float f32x4 __attribute__((ext_vector_type(4)));
typedef short short8 __attribute__((ext_vector_type(8)));

__device__ __forceinline__ unsigned short f2bf(float f) {
    unsigned int x = __float_as_uint(f);
    return (unsigned short)((x + 0x7FFFu + ((x >> 16) & 1u)) >> 16);  // RNE
}

// ---------------- prep: transpose+bf16 weights, zero cur + stats ----------------
__global__ void prep_kernel(const float* __restrict__ W1, const float* __restrict__ W2,
                            unsigned short* __restrict__ WT1, unsigned short* __restrict__ WT2,
                            int* __restrict__ cur, float* __restrict__ stats) {
    int idx = blockIdx.x * blockDim.x + threadIdx.x;
    if (idx < D * D) {
        int col = idx >> 7, k = idx & 127;
        WT1[col * D + k] = f2bf(W1[k * D + col]);
        WT2[col * D + k] = f2bf(W2[k * D + col]);
    }
    if (idx < N_NODES) cur[idx] = 0;
    if (idx < 4 * D) stats[idx] = 0.0f;
}

// ---------------- build ELL adjacency: dst -> list of src (int) ----------------
__global__ void scatter_kernel(const int* __restrict__ srcI, const int* __restrict__ dstI,
                               int* __restrict__ cur, int* __restrict__ ell) {
    int e = blockIdx.x * blockDim.x + threadIdx.x;
    if (e >= N_EDGES) return;
    int d = dstI[e];
    int pos = atomicAdd(&cur[d], 1);
    if (pos < ELLW) ell[(size_t)d * ELLW + pos] = srcI[e];
}

// ---------------- weight-stationary MFMA GEMM (R10-proven) ----------------
// WT (128x128 bf16, 32KB) VGPR-resident per wave. Grid-stride over 16-row tiles.
// OUT_BF16: write C as bf16 (for h2, halves gather traffic).
template<bool BN, bool HAS_BIAS, bool STATS, bool OUT_BF16>
__global__ __launch_bounds__(256, 2) void gemm_ws_kernel(
    const float* __restrict__ A, const unsigned short* __restrict__ WT,
    const float* __restrict__ bn_sum, const float* __restrict__ bn_sq,
    const float* __restrict__ bn_gamma, const float* __restrict__ bn_beta,
    const float* __restrict__ out_bias, float* __restrict__ C,
    unsigned short* __restrict__ Cb, int M,
    float* __restrict__ sum_out, float* __restrict__ sq_out)
{
    __shared__ __align__(16) float scs[D];
    __shared__ __align__(16) float bis[D];
    __shared__ float ssum[D];
    __shared__ float ssq[D];

    const int tid  = threadIdx.x;
    const int lane = tid & 63;
    const int w    = tid >> 6;
    const int l15  = lane & 15;
    const int lg   = lane >> 4;

    if (BN) {
        if (tid < D) {
            const float inv_n = 1.0f / (float)N_NODES;
            float mean = bn_sum[tid] * inv_n;
            float var  = bn_sq[tid] * inv_n - mean * mean;
            float rstd = rsqrtf(var + BN_EPS);
            float sc = bn_gamma[tid] * rstd;
            scs[tid] = sc;
            bis[tid] = bn_beta[tid] - mean * sc;
        }
    }
    if (STATS) {
        if (tid < D) { ssum[tid] = 0.f; ssq[tid] = 0.f; }
    }
    if (BN || STATS) __syncthreads();

    // B fragments: one-time load, stays in registers for the whole kernel
    short8 b[8][4];
    #pragma unroll
    for (int ct = 0; ct < 8; ++ct)
        #pragma unroll
        for (int ks = 0; ks < 4; ++ks)
            b[ct][ks] = *(const short8*)&WT[(size_t)(ct * 16 + l15) * D + ks * 32 + lg * 8];

    float ob[8];
    #pragma unroll
    for (int ct = 0; ct < 8; ++ct) ob[ct] = HAS_BIAS ? out_bias[ct * 16 + l15] : 0.f;

    float psum[8], psq[8];
    #pragma unroll
    for (int ct = 0; ct < 8; ++ct) { psum[ct] = 0.f; psq[ct] = 0.f; }

    const int nt = (M + 15) / 16;   // 3125 row tiles
    for (int t = blockIdx.x * 4 + w; t < nt; t += gridDim.x * 4) {
        int ar = t * 16 + l15; if (ar > M - 1) ar = M - 1;
        short8 af[4];
        #pragma unroll
        for (int ks = 0; ks < 4; ++ks) {
            const int kb = ks * 32 + lg * 8;
            const float* ap = &A[(size_t)ar * D + kb];
            float4 v0 = *(const float4*)ap;
            float4 v1 = *(const float4*)(ap + 4);
            float vv[8] = {v0.x, v0.y, v0.z, v0.w, v1.x, v1.y, v1.z, v1.w};
            short8 a8;
            #pragma unroll
            for (int j = 0; j < 8; ++j) {
                float f = vv[j];
                if (BN) f = fmaxf(fmaf(f, scs[kb + j], bis[kb + j]), 0.f);
                a8[j] = (short)f2bf(f);
            }
            af[ks] = a8;
        }

        f32x4 acc[8];
        #pragma unroll
        for (int ct = 0; ct < 8; ++ct) acc[ct] = (f32x4){0.f, 0.f, 0.f, 0.f};
        #pragma unroll
        for (int ks = 0; ks < 4; ++ks)
            #pragma unroll
            for (int ct = 0; ct < 8; ++ct)
                acc[ct] = __builtin_amdgcn_mfma_f32_16x16x32_bf16(af[ks], b[ct][ks], acc[ct], 0, 0, 0);

        // C/D layout: col = ct*16 + l15, row = t*16 + lg*4 + j
        const int rb2 = t * 16 + lg * 4;
        #pragma unroll
        for (int j = 0; j < 4; ++j) {
            const int row = rb2 + j;
            if (row < M) {
                #pragma unroll
                for (int ct = 0; ct < 8; ++ct) {
                    float o = acc[ct][j] + ob[ct];
                    if (OUT_BF16) Cb[(size_t)row * D + ct * 16 + l15] = f2bf(o);
                    else          C[(size_t)row * D + ct * 16 + l15] = o;
                    if (STATS) { psum[ct] += o; psq[ct] = fmaf(o, o, psq[ct]); }
                }
            }
        }
    }

    if (STATS) {
        #pragma unroll
        for (int ct = 0; ct < 8; ++ct) {
            atomicAdd(&ssum[ct * 16 + l15], psum[ct]);
            atomicAdd(&ssq[ct * 16 + l15], psq[ct]);
        }
        __syncthreads();
        if (tid < D) {
            unsafeAtomicAdd(&sum_out[tid], ssum[tid]);
            unsafeAtomicAdd(&sq_out[tid], ssq[tid]);
        }
    }
}

// bf16-pair load helper: word -> two floats
__device__ __forceinline__ void bfp(unsigned pv, float& fx, float& fy) {
    fx = __uint_as_float(pv << 16);
    fy = __uint_as_float(pv & 0xFFFF0000u);
}

// ---------------- gather over bf16 h2: TWO nodes per wave, 4-edge unroll ----------------
// degree weights computed on the fly from cnt (no dinv array)
__global__ __launch_bounds__(256) void gather_kernel(
    const int* __restrict__ ell, const int* __restrict__ cnt,
    const unsigned short* __restrict__ h2b,
    const float* __restrict__ b_conv, float* __restrict__ outpre,
    float* __restrict__ sum_out, float* __restrict__ sq_out)
{
    const int lane = threadIdx.x & 63;
    const int wid  = threadIdx.x >> 6;
    const int col  = lane * 2;
    const float2 bc = *(const float2*)&b_conv[col];
    float2 sum = make_float2(0.f, 0.f);
    float2 sq  = make_float2(0.f, 0.f);

    for (int d0 = blockIdx.x * 8 + wid * 2; d0 < N_NODES; d0 += gridDim.x * 8) {
        const int d1 = d0 + 1;
        int cAr = cnt[d0];
        int cBr = cnt[d1];
        const float ddA = rsqrtf((float)cAr + 1.0f);
        const float ddB = rsqrtf((float)cBr + 1.0f);
        int cA = cAr > ELLW ? ELLW : cAr;
        int cB = cBr > ELLW ? ELLW : cBr;
        float hAx, hAy, hBx, hBy;
        bfp(*(const unsigned*)&h2b[(size_t)d0 * D + col], hAx, hAy);
        bfp(*(const unsigned*)&h2b[(size_t)d1 * D + col], hBx, hBy);
        float2 accA, accB;
        accA.x = ddA * hAx; accA.y = ddA * hAy;
        accB.x = ddB * hBx; accB.y = ddB * hBy;

        int slA = 0, slB = 0;
        float wlA = 0.f, wlB = 0.f;
        if (lane < cA) { slA = ell[(size_t)d0 * ELLW + lane]; wlA = rsqrtf((float)cnt[slA] + 1.0f); }
        if (lane < cB) { slB = ell[(size_t)d1 * ELLW + lane]; wlB = rsqrtf((float)cnt[slB] + 1.0f); }

        const int cmin = cA < cB ? cA : cB;
        int j = 0;
        for (; j + 4 <= cmin; j += 4) {
            unsigned pA[4], pB[4];
            float wA[4], wB[4];
            #pragma unroll
            for (int u = 0; u < 4; ++u) {
                int sA = __shfl(slA, j + u);
                int sB = __shfl(slB, j + u);
                wA[u] = __shfl(wlA, j + u);
                wB[u] = __shfl(wlB, j + u);
                pA[u] = *(const unsigned*)&h2b[(size_t)sA * D + col];
                pB[u] = *(const unsigned*)&h2b[(size_t)sB * D + col];
            }
            #pragma unroll
            for (int u = 0; u < 4; ++u) {
                float ax, ay, bx, by;
                bfp(pA[u], ax, ay);
                bfp(pB[u], bx, by);
                accA.x = fmaf(wA[u], ax, accA.x);
                accA.y = fmaf(wA[u], ay, accA.y);
                accB.x = fmaf(wB[u], bx, accB.x);
                accB.y = fmaf(wB[u], by, accB.y);
            }
        }
        int jA = j, jB = j;
        for (; jA < cA; ++jA) {
            int s = __shfl(slA, jA);
            float ww = __shfl(wlA, jA);
            float ax, ay;
            bfp(*(const unsigned*)&h2b[(size_t)s * D + col], ax, ay);
            accA.x = fmaf(ww, ax, accA.x);
            accA.y = fmaf(ww, ay, accA.y);
        }
        for (; jB < cB; ++jB) {
            int s = __shfl(slB, jB);
            float ww = __shfl(wlB, jB);
            float bx, by;
            bfp(*(const unsigned*)&h2b[(size_t)s * D + col], bx, by);
            accB.x = fmaf(ww, bx, accB.x);
            accB.y = fmaf(ww, by, accB.y);
        }

        float2 oA, oB;
        oA.x = fmaf(ddA, accA.x, bc.x);
        oA.y = fmaf(ddA, accA.y, bc.y);
        oB.x = fmaf(ddB, accB.x, bc.x);
        oB.y = fmaf(ddB, accB.y, bc.y);
        *(float2*)&outpre[(size_t)d0 * D + col] = oA;
        *(float2*)&outpre[(size_t)d1 * D + col] = oB;
        sum.x += oA.x + oB.x; sum.y += oA.y + oB.y;
        sq.x = fmaf(oA.x, oA.x, sq.x); sq.x = fmaf(oB.x, oB.x, sq.x);
        sq.y = fmaf(oA.y, oA.y, sq.y); sq.y = fmaf(oB.y, oB.y, sq.y);
    }

    __shared__ float2 sS[256];
    __shared__ float2 qS[256];
    sS[threadIdx.x] = sum; qS[threadIdx.x] = sq;
    __syncthreads();
    if (wid == 0) {
        #pragma unroll
        for (int w = 1; w < 4; ++w) {
            float2 s2 = sS[w * 64 + lane];
            float2 q2 = qS[w * 64 + lane];
            sum.x += s2.x; sum.y += s2.y;
            sq.x += q2.x; sq.y += q2.y;
        }
        unsafeAtomicAdd(&sum_out[col + 0], sum.x);
        unsafeAtomicAdd(&sum_out[col + 1], sum.y);
        unsafeAtomicAdd(&sq_out[col + 0], sq.x);
        unsafeAtomicAdd(&sq_out[col + 1], sq.y);
    }
}

// ---------------- final: out = relu(out*scale2 + bias2), scale/bias from raw stats ----------------
__global__ void final_kernel(float* __restrict__ out,
        const float* __restrict__ s_sum, const float* __restrict__ s_sq,
        const float* __restrict__ gamma, const float* __restrict__ beta) {
    __shared__ __align__(16) float scs[D];
    __shared__ __align__(16) float bis[D];
    const int tid = threadIdx.x;
    if (tid < D) {
        const float inv_n = 1.0f / (float)N_NODES;
        float mean = s_sum[tid] * inv_n;
        float var  = s_sq[tid] * inv_n - mean * mean;
        float rstd = rsqrtf(var + BN_EPS);
        float sc = gamma[tid] * rstd;
        scs[tid] = sc;
        bis[tid] = beta[tid] - mean * sc;
    }
    __syncthreads();
    const int t = blockIdx.x * blockDim.x + tid;
    const int c4 = t & 31;
    float4 sc = *(const float4*)&scs[c4 * 4];
    float4 bi = *(const float4*)&bis[c4 * 4];
    const int total = N_NODES * D / 4;
    const int stride = gridDim.x * blockDim.x;
    for (int i = t; i < total; i += stride) {
        float4 v = ((const float4*)out)[i];
        v.x = fmaxf(fmaf(v.x, sc.x, bi.x), 0.f);
        v.y = fmaxf(fmaf(v.y, sc.y, bi.y), 0.f);
        v.z = fmaxf(fmaf(v.z, sc.z, bi.z), 0.f);
        v.w = fmaxf(fmaf(v.w, sc.w, bi.w), 0.f);
        ((float4*)out)[i] = v;
    }
}

extern "C" void kernel_launch(void* const* d_in, const int* in_sizes, int n_in,
                              void* d_out, int out_size, void* d_ws, size_t ws_size,
                              hipStream_t stream) {
    const float* x      = (const float*)d_in[0];
    const int*   edge   = (const int*)d_in[1];      // [2][N_EDGES], row0=src, row1=dst
    const float* W_mlp  = (const float*)d_in[2];
    const float* b_mlp  = (const float*)d_in[3];
    const float* gamma1 = (const float*)d_in[4];
    const float* beta1  = (const float*)d_in[5];
    const float* W_conv = (const float*)d_in[6];
    const float* b_conv = (const float*)d_in[7];
    const float* gamma2 = (const float*)d_in[8];
    const float* beta2  = (const float*)d_in[9];
    float* out = (float*)d_out;

    float* ws = (float*)d_ws;
    float* h1   = ws;                                  // N*D floats (25.6 MB)
    unsigned short* h2b = (unsigned short*)(ws + (size_t)N_NODES * D);  // N*D bf16 (12.8 MB)
    int*   ell  = (int*)h1;                            // alias: h1 dead after gemm2 (12.8MB)
    float* extra = ws + 2 * (size_t)N_NODES * D;
    int*   cur  = (int*)extra;                         // N ints (ELL cursors / in-degree)
    float* stats = extra + N_NODES;                    // 4*D
    float* sum1 = stats;         float* sq1 = stats + D;
    float* sum2 = stats + 2 * D; float* sq2 = stats + 3 * D;
    unsigned short* WT1 = (unsigned short*)(stats + 4 * D);   // 128*128 bf16
    unsigned short* WT2 = WT1 + D * D;

    const int* srcI = edge;
    const int* dstI = edge + N_EDGES;

    prep_kernel<<<(N_NODES + 255) / 256, 256, 0, stream>>>(W_mlp, W_conv, WT1, WT2, cur, stats);

    gemm_ws_kernel<false, true, true, false><<<392, 256, 0, stream>>>(
        x, WT1, nullptr, nullptr, nullptr, nullptr, b_mlp, h1, nullptr, N_NODES, sum1, sq1);

    gemm_ws_kernel<true, false, false, true><<<392, 256, 0, stream>>>(
        h1, WT2, sum1, sq1, gamma1, beta1, nullptr, nullptr, h2b, N_NODES, nullptr, nullptr);

    // h1 is dead now: build src ELL in its place
    scatter_kernel<<<(N_EDGES + 255) / 256, 256, 0, stream>>>(srcI, dstI, cur, ell);

    gather_kernel<<<2048, 256, 0, stream>>>(ell, cur, h2b, b_conv, out, sum2, sq2);

    final_kernel<<<2048, 256, 0, stream>>>(out, sum2, sq2, gamma2, beta2);
}

// Round 13
// 286.536 us; speedup vs baseline: 1.1438x; 1.0387x over previous
//
#include <hip/hip_runtime.h>
#include <math.h>

#define N_NODES 50000
#define N_EDGES 600000
#define D 128
#define BN_EPS 1e-5f
#define ELLW 64

typedef float f32x4 __attribute__((ext_vector_type(4)));
typedef short short8 __attribute__((ext_vector_type(8)));

__device__ __forceinline__ unsigned short f2bf(float f) {
    unsigned int x = __float_as_uint(f);
    return (unsigned short)((x + 0x7FFFu + ((x >> 16) & 1u)) >> 16);  // RNE
}

// ---------------- prep: transpose+bf16 weights, zero cur + stats ----------------
__global__ void prep_kernel(const float* __restrict__ W1, const float* __restrict__ W2,
                            unsigned short* __restrict__ WT1, unsigned short* __restrict__ WT2,
                            int* __restrict__ cur, float* __restrict__ stats) {
    int idx = blockIdx.x * blockDim.x + threadIdx.x;
    if (idx < D * D) {
        int col = idx >> 7, k = idx & 127;
        WT1[col * D + k] = f2bf(W1[k * D + col]);
        WT2[col * D + k] = f2bf(W2[k * D + col]);
    }
    if (idx < N_NODES) cur[idx] = 0;
    if (idx < 4 * D) stats[idx] = 0.0f;
}

// ---------------- build ELL adjacency: dst -> list of src (int) ----------------
__global__ void scatter_kernel(const int* __restrict__ srcI, const int* __restrict__ dstI,
                               int* __restrict__ cur, int* __restrict__ ell) {
    int e = blockIdx.x * blockDim.x + threadIdx.x;
    if (e >= N_EDGES) return;
    int d = dstI[e];
    int pos = atomicAdd(&cur[d], 1);
    if (pos < ELLW) ell[(size_t)d * ELLW + pos] = srcI[e];
}

// ---------------- half-width weight-stationary MFMA GEMM ----------------
// Wave owns a FIXED 64-col half (waves 0-1: cols 0-63, waves 2-3: cols 64-127):
// b[4][4] short8 = 64 VGPR -> ~120 total -> 4 waves/SIMD (launch_bounds 256,4).
// Paired waves share A rows (L1 reuse). Grid-stride over 16-row tiles.
// IN_BF16: A read as bf16 (unpack f32 for BN). OUT_BF16: C written bf16.
template<bool BN, bool HAS_BIAS, bool STATS, bool IN_BF16, bool OUT_BF16>
__global__ __launch_bounds__(256, 4) void gemm_hw_kernel(
    const float* __restrict__ Af, const unsigned short* __restrict__ Ab,
    const unsigned short* __restrict__ WT,
    const float* __restrict__ bn_sum, const float* __restrict__ bn_sq,
    const float* __restrict__ bn_gamma, const float* __restrict__ bn_beta,
    const float* __restrict__ out_bias, float* __restrict__ C,
    unsigned short* __restrict__ Cb, int M,
    float* __restrict__ sum_out, float* __restrict__ sq_out)
{
    __shared__ __align__(16) float scs[D];
    __shared__ __align__(16) float bis[D];
    __shared__ float ssum[D];
    __shared__ float ssq[D];

    const int tid  = threadIdx.x;
    const int lane = tid & 63;
    const int w    = tid >> 6;
    const int l15  = lane & 15;
    const int lg   = lane >> 4;
    const int colbase = (w >> 1) * 64;    // wave-fixed column half

    if (BN) {
        if (tid < D) {
            const float inv_n = 1.0f / (float)N_NODES;
            float mean = bn_sum[tid] * inv_n;
            float var  = bn_sq[tid] * inv_n - mean * mean;
            float rstd = rsqrtf(var + BN_EPS);
            float sc = bn_gamma[tid] * rstd;
            scs[tid] = sc;
            bis[tid] = bn_beta[tid] - mean * sc;
        }
    }
    if (STATS) {
        if (tid < D) { ssum[tid] = 0.f; ssq[tid] = 0.f; }
    }
    if (BN || STATS) __syncthreads();

    // B fragments for this wave's 64 columns: 64 VGPRs, loaded once
    short8 b[4][4];
    #pragma unroll
    for (int ct = 0; ct < 4; ++ct)
        #pragma unroll
        for (int ks = 0; ks < 4; ++ks)
            b[ct][ks] = *(const short8*)&WT[(size_t)(colbase + ct * 16 + l15) * D + ks * 32 + lg * 8];

    float ob[4];
    #pragma unroll
    for (int ct = 0; ct < 4; ++ct) ob[ct] = HAS_BIAS ? out_bias[colbase + ct * 16 + l15] : 0.f;

    float psum[4], psq[4];
    #pragma unroll
    for (int ct = 0; ct < 4; ++ct) { psum[ct] = 0.f; psq[ct] = 0.f; }

    const int nt = (M + 15) / 16;   // 3125 row tiles
    for (int t = blockIdx.x * 2 + (w & 1); t < nt; t += gridDim.x * 2) {
        int ar = t * 16 + l15; if (ar > M - 1) ar = M - 1;
        short8 af[4];
        #pragma unroll
        for (int ks = 0; ks < 4; ++ks) {
            const int kb = ks * 32 + lg * 8;
            float vv[8];
            if (IN_BF16) {
                short8 raw = *(const short8*)&Ab[(size_t)ar * D + kb];
                #pragma unroll
                for (int j = 0; j < 8; ++j)
                    vv[j] = __uint_as_float(((unsigned)(unsigned short)raw[j]) << 16);
            } else {
                const float* ap = &Af[(size_t)ar * D + kb];
                float4 v0 = *(const float4*)ap;
                float4 v1 = *(const float4*)(ap + 4);
                vv[0] = v0.x; vv[1] = v0.y; vv[2] = v0.z; vv[3] = v0.w;
                vv[4] = v1.x; vv[5] = v1.y; vv[6] = v1.z; vv[7] = v1.w;
            }
            short8 a8;
            #pragma unroll
            for (int j = 0; j < 8; ++j) {
                float f = vv[j];
                if (BN) f = fmaxf(fmaf(f, scs[kb + j], bis[kb + j]), 0.f);
                a8[j] = (short)f2bf(f);
            }
            af[ks] = a8;
        }

        f32x4 acc[4];
        #pragma unroll
        for (int ct = 0; ct < 4; ++ct) acc[ct] = (f32x4){0.f, 0.f, 0.f, 0.f};
        #pragma unroll
        for (int ks = 0; ks < 4; ++ks)
            #pragma unroll
            for (int ct = 0; ct < 4; ++ct)
                acc[ct] = __builtin_amdgcn_mfma_f32_16x16x32_bf16(af[ks], b[ct][ks], acc[ct], 0, 0, 0);

        // C/D layout: col = colbase + ct*16 + l15, row = t*16 + lg*4 + j
        const int rb2 = t * 16 + lg * 4;
        #pragma unroll
        for (int j = 0; j < 4; ++j) {
            const int row = rb2 + j;
            if (row < M) {
                #pragma unroll
                for (int ct = 0; ct < 4; ++ct) {
                    float o = acc[ct][j] + ob[ct];
                    if (OUT_BF16) Cb[(size_t)row * D + colbase + ct * 16 + l15] = f2bf(o);
                    else          C[(size_t)row * D + colbase + ct * 16 + l15] = o;
                    if (STATS) { psum[ct] += o; psq[ct] = fmaf(o, o, psq[ct]); }
                }
            }
        }
    }

    if (STATS) {
        #pragma unroll
        for (int ct = 0; ct < 4; ++ct) {
            atomicAdd(&ssum[colbase + ct * 16 + l15], psum[ct]);
            atomicAdd(&ssq[colbase + ct * 16 + l15], psq[ct]);
        }
        __syncthreads();
        if (tid < D) {
            unsafeAtomicAdd(&sum_out[tid], ssum[tid]);
            unsafeAtomicAdd(&sq_out[tid], ssq[tid]);
        }
    }
}

// bf16-pair load helper: word -> two floats
__device__ __forceinline__ void bfp(unsigned pv, float& fx, float& fy) {
    fx = __uint_as_float(pv << 16);
    fy = __uint_as_float(pv & 0xFFFF0000u);
}

// ---------------- gather over bf16 h2: TWO nodes per wave, 4-edge unroll (grid 1024 FINAL) ----------------
__global__ __launch_bounds__(256) void gather_kernel(
    const int* __restrict__ ell, const int* __restrict__ cnt,
    const unsigned short* __restrict__ h2b,
    const float* __restrict__ b_conv, float* __restrict__ outpre,
    float* __restrict__ sum_out, float* __restrict__ sq_out)
{
    const int lane = threadIdx.x & 63;
    const int wid  = threadIdx.x >> 6;
    const int col  = lane * 2;
    const float2 bc = *(const float2*)&b_conv[col];
    float2 sum = make_float2(0.f, 0.f);
    float2 sq  = make_float2(0.f, 0.f);

    for (int d0 = blockIdx.x * 8 + wid * 2; d0 < N_NODES; d0 += gridDim.x * 8) {
        const int d1 = d0 + 1;
        int cAr = cnt[d0];
        int cBr = cnt[d1];
        const float ddA = rsqrtf((float)cAr + 1.0f);
        const float ddB = rsqrtf((float)cBr + 1.0f);
        int cA = cAr > ELLW ? ELLW : cAr;
        int cB = cBr > ELLW ? ELLW : cBr;
        float hAx, hAy, hBx, hBy;
        bfp(*(const unsigned*)&h2b[(size_t)d0 * D + col], hAx, hAy);
        bfp(*(const unsigned*)&h2b[(size_t)d1 * D + col], hBx, hBy);
        float2 accA, accB;
        accA.x = ddA * hAx; accA.y = ddA * hAy;
        accB.x = ddB * hBx; accB.y = ddB * hBy;

        int slA = 0, slB = 0;
        float wlA = 0.f, wlB = 0.f;
        if (lane < cA) { slA = ell[(size_t)d0 * ELLW + lane]; wlA = rsqrtf((float)cnt[slA] + 1.0f); }
        if (lane < cB) { slB = ell[(size_t)d1 * ELLW + lane]; wlB = rsqrtf((float)cnt[slB] + 1.0f); }

        const int cmin = cA < cB ? cA : cB;
        int j = 0;
        for (; j + 4 <= cmin; j += 4) {
            unsigned pA[4], pB[4];
            float wA[4], wB[4];
            #pragma unroll
            for (int u = 0; u < 4; ++u) {
                int sA = __shfl(slA, j + u);
                int sB = __shfl(slB, j + u);
                wA[u] = __shfl(wlA, j + u);
                wB[u] = __shfl(wlB, j + u);
                pA[u] = *(const unsigned*)&h2b[(size_t)sA * D + col];
                pB[u] = *(const unsigned*)&h2b[(size_t)sB * D + col];
            }
            #pragma unroll
            for (int u = 0; u < 4; ++u) {
                float ax, ay, bx, by;
                bfp(pA[u], ax, ay);
                bfp(pB[u], bx, by);
                accA.x = fmaf(wA[u], ax, accA.x);
                accA.y = fmaf(wA[u], ay, accA.y);
                accB.x = fmaf(wB[u], bx, accB.x);
                accB.y = fmaf(wB[u], by, accB.y);
            }
        }
        int jA = j, jB = j;
        for (; jA < cA; ++jA) {
            int s = __shfl(slA, jA);
            float ww = __shfl(wlA, jA);
            float ax, ay;
            bfp(*(const unsigned*)&h2b[(size_t)s * D + col], ax, ay);
            accA.x = fmaf(ww, ax, accA.x);
            accA.y = fmaf(ww, ay, accA.y);
        }
        for (; jB < cB; ++jB) {
            int s = __shfl(slB, jB);
            float ww = __shfl(wlB, jB);
            float bx, by;
            bfp(*(const unsigned*)&h2b[(size_t)s * D + col], bx, by);
            accB.x = fmaf(ww, bx, accB.x);
            accB.y = fmaf(ww, by, accB.y);
        }

        float2 oA, oB;
        oA.x = fmaf(ddA, accA.x, bc.x);
        oA.y = fmaf(ddA, accA.y, bc.y);
        oB.x = fmaf(ddB, accB.x, bc.x);
        oB.y = fmaf(ddB, accB.y, bc.y);
        *(float2*)&outpre[(size_t)d0 * D + col] = oA;
        *(float2*)&outpre[(size_t)d1 * D + col] = oB;
        sum.x += oA.x + oB.x; sum.y += oA.y + oB.y;
        sq.x = fmaf(oA.x, oA.x, sq.x); sq.x = fmaf(oB.x, oB.x, sq.x);
        sq.y = fmaf(oA.y, oA.y, sq.y); sq.y = fmaf(oB.y, oB.y, sq.y);
    }

    __shared__ float2 sS[256];
    __shared__ float2 qS[256];
    sS[threadIdx.x] = sum; qS[threadIdx.x] = sq;
    __syncthreads();
    if (wid == 0) {
        #pragma unroll
        for (int w = 1; w < 4; ++w) {
            float2 s2 = sS[w * 64 + lane];
            float2 q2 = qS[w * 64 + lane];
            sum.x += s2.x; sum.y += s2.y;
            sq.x += q2.x; sq.y += q2.y;
        }
        unsafeAtomicAdd(&sum_out[col + 0], sum.x);
        unsafeAtomicAdd(&sum_out[col + 1], sum.y);
        unsafeAtomicAdd(&sq_out[col + 0], sq.x);
        unsafeAtomicAdd(&sq_out[col + 1], sq.y);
    }
}

// ---------------- final: out = relu(out*scale2 + bias2), scale/bias from raw stats ----------------
__global__ void final_kernel(float* __restrict__ out,
        const float* __restrict__ s_sum, const float* __restrict__ s_sq,
        const float* __restrict__ gamma, const float* __restrict__ beta) {
    __shared__ __align__(16) float scs[D];
    __shared__ __align__(16) float bis[D];
    const int tid = threadIdx.x;
    if (tid < D) {
        const float inv_n = 1.0f / (float)N_NODES;
        float mean = s_sum[tid] * inv_n;
        float var  = s_sq[tid] * inv_n - mean * mean;
        float rstd = rsqrtf(var + BN_EPS);
        float sc = gamma[tid] * rstd;
        scs[tid] = sc;
        bis[tid] = beta[tid] - mean * sc;
    }
    __syncthreads();
    const int t = blockIdx.x * blockDim.x + tid;
    const int c4 = t & 31;
    float4 sc = *(const float4*)&scs[c4 * 4];
    float4 bi = *(const float4*)&bis[c4 * 4];
    const int total = N_NODES * D / 4;
    const int stride = gridDim.x * blockDim.x;
    for (int i = t; i < total; i += stride) {
        float4 v = ((const float4*)out)[i];
        v.x = fmaxf(fmaf(v.x, sc.x, bi.x), 0.f);
        v.y = fmaxf(fmaf(v.y, sc.y, bi.y), 0.f);
        v.z = fmaxf(fmaf(v.z, sc.z, bi.z), 0.f);
        v.w = fmaxf(fmaf(v.w, sc.w, bi.w), 0.f);
        ((float4*)out)[i] = v;
    }
}

extern "C" void kernel_launch(void* const* d_in, const int* in_sizes, int n_in,
                              void* d_out, int out_size, void* d_ws, size_t ws_size,
                              hipStream_t stream) {
    const float* x      = (const float*)d_in[0];
    const int*   edge   = (const int*)d_in[1];      // [2][N_EDGES], row0=src, row1=dst
    const float* W_mlp  = (const float*)d_in[2];
    const float* b_mlp  = (const float*)d_in[3];
    const float* gamma1 = (const float*)d_in[4];
    const float* beta1  = (const float*)d_in[5];
    const float* W_conv = (const float*)d_in[6];
    const float* b_conv = (const float*)d_in[7];
    const float* gamma2 = (const float*)d_in[8];
    const float* beta2  = (const float*)d_in[9];
    float* out = (float*)d_out;

    float* ws = (float*)d_ws;
    unsigned short* h1b = (unsigned short*)ws;                      // N*D bf16 (12.8 MB)
    unsigned short* h2b = (unsigned short*)(ws + (size_t)N_NODES * D / 2);  // N*D bf16 (12.8 MB)
    int*   ell  = (int*)h1b;                           // alias: h1b dead after gemm2 (12.8MB exact)
    float* extra = ws + (size_t)N_NODES * D;           // beyond h1b+h2b
    int*   cur  = (int*)extra;                         // N ints (ELL cursors / in-degree)
    float* stats = extra + N_NODES;                    // 4*D
    float* sum1 = stats;         float* sq1 = stats + D;
    float* sum2 = stats + 2 * D; float* sq2 = stats + 3 * D;
    unsigned short* WT1 = (unsigned short*)(stats + 4 * D);   // 128*128 bf16
    unsigned short* WT2 = WT1 + D * D;

    const int* srcI = edge;
    const int* dstI = edge + N_EDGES;

    prep_kernel<<<(N_NODES + 255) / 256, 256, 0, stream>>>(W_mlp, W_conv, WT1, WT2, cur, stats);

    gemm_hw_kernel<false, true, true, false, true><<<1024, 256, 0, stream>>>(
        x, nullptr, WT1, nullptr, nullptr, nullptr, nullptr, b_mlp, nullptr, h1b, N_NODES, sum1, sq1);

    gemm_hw_kernel<true, false, false, true, true><<<1024, 256, 0, stream>>>(
        nullptr, h1b, WT2, sum1, sq1, gamma1, beta1, nullptr, nullptr, h2b, N_NODES, nullptr, nullptr);

    // h1b is dead now: build src ELL in its place
    scatter_kernel<<<(N_EDGES + 255) / 256, 256, 0, stream>>>(srcI, dstI, cur, ell);

    gather_kernel<<<1024, 256, 0, stream>>>(ell, cur, h2b, b_conv, out, sum2, sq2);

    final_kernel<<<2048, 256, 0, stream>>>(out, sum2, sq2, gamma2, beta2);
}

// Round 14
// 213.584 us; speedup vs baseline: 1.5345x; 1.3416x over previous
//
#include <hip/hip_runtime.h>
#include <math.h>

#define N_NODES 50000
#define N_EDGES 600000
#define D 128
#define BN_EPS 1e-5f
#define ELLW 64
#define NREP 16   // stats replica count (atomic-contention spreading)

typedef float f32x4 __attribute__((ext_vector_type(4)));
typedef short short8 __attribute__((ext_vector_type(8)));

__device__ __forceinline__ unsigned short f2bf(float f) {
    unsigned int x = __float_as_uint(f);
    return (unsigned short)((x + 0x7FFFu + ((x >> 16) & 1u)) >> 16);  // RNE
}

// ---------------- prep: transpose+bf16 weights, zero cur + replicated stats ----------------
__global__ void prep_kernel(const float* __restrict__ W1, const float* __restrict__ W2,
                            unsigned short* __restrict__ WT1, unsigned short* __restrict__ WT2,
                            int* __restrict__ cur, float* __restrict__ stats) {
    int idx = blockIdx.x * blockDim.x + threadIdx.x;
    if (idx < D * D) {
        int col = idx >> 7, k = idx & 127;
        WT1[col * D + k] = f2bf(W1[k * D + col]);
        WT2[col * D + k] = f2bf(W2[k * D + col]);
    }
    if (idx < N_NODES) cur[idx] = 0;
    if (idx < NREP * 4 * D) stats[idx] = 0.0f;
}

// ---------------- build ELL adjacency: dst -> list of src (int) ----------------
__global__ void scatter_kernel(const int* __restrict__ srcI, const int* __restrict__ dstI,
                               int* __restrict__ cur, int* __restrict__ ell) {
    int e = blockIdx.x * blockDim.x + threadIdx.x;
    if (e >= N_EDGES) return;
    int d = dstI[e];
    int pos = atomicAdd(&cur[d], 1);
    if (pos < ELLW) ell[(size_t)d * ELLW + pos] = srcI[e];
}

// ---------------- weight-stationary MFMA GEMM (R10-proven structure) ----------------
// WT (128x128 bf16, 32KB) VGPR-resident per wave. Grid-stride over 16-row tiles, 392 blocks.
// IN_BF16: A read bf16; OUT_BF16: C written bf16. Stats: replicated atomics (blockIdx&15).
template<bool BN, bool HAS_BIAS, bool STATS, bool IN_BF16, bool OUT_BF16>
__global__ __launch_bounds__(256, 2) void gemm_ws_kernel(
    const float* __restrict__ Af, const unsigned short* __restrict__ Ab,
    const unsigned short* __restrict__ WT,
    const float* __restrict__ bn_sum, const float* __restrict__ bn_sq,
    const float* __restrict__ bn_gamma, const float* __restrict__ bn_beta,
    const float* __restrict__ out_bias, float* __restrict__ C,
    unsigned short* __restrict__ Cb, int M,
    float* __restrict__ sum_out, float* __restrict__ sq_out)
{
    __shared__ __align__(16) float scs[D];
    __shared__ __align__(16) float bis[D];
    __shared__ float ssum[D];
    __shared__ float ssq[D];

    const int tid  = threadIdx.x;
    const int lane = tid & 63;
    const int w    = tid >> 6;
    const int l15  = lane & 15;
    const int lg   = lane >> 4;

    if (BN) {
        if (tid < D) {
            float s = 0.f, q = 0.f;
            #pragma unroll
            for (int r = 0; r < NREP; ++r) { s += bn_sum[r * D + tid]; q += bn_sq[r * D + tid]; }
            const float inv_n = 1.0f / (float)N_NODES;
            float mean = s * inv_n;
            float var  = q * inv_n - mean * mean;
            float rstd = rsqrtf(var + BN_EPS);
            float sc = bn_gamma[tid] * rstd;
            scs[tid] = sc;
            bis[tid] = bn_beta[tid] - mean * sc;
        }
    }
    if (STATS) {
        if (tid < D) { ssum[tid] = 0.f; ssq[tid] = 0.f; }
    }
    if (BN || STATS) __syncthreads();

    // B fragments: one-time load, stays in registers for the whole kernel
    short8 b[8][4];
    #pragma unroll
    for (int ct = 0; ct < 8; ++ct)
        #pragma unroll
        for (int ks = 0; ks < 4; ++ks)
            b[ct][ks] = *(const short8*)&WT[(size_t)(ct * 16 + l15) * D + ks * 32 + lg * 8];

    float ob[8];
    #pragma unroll
    for (int ct = 0; ct < 8; ++ct) ob[ct] = HAS_BIAS ? out_bias[ct * 16 + l15] : 0.f;

    float psum[8], psq[8];
    #pragma unroll
    for (int ct = 0; ct < 8; ++ct) { psum[ct] = 0.f; psq[ct] = 0.f; }

    const int nt = (M + 15) / 16;   // 3125 row tiles
    for (int t = blockIdx.x * 4 + w; t < nt; t += gridDim.x * 4) {
        int ar = t * 16 + l15; if (ar > M - 1) ar = M - 1;
        short8 af[4];
        #pragma unroll
        for (int ks = 0; ks < 4; ++ks) {
            const int kb = ks * 32 + lg * 8;
            float vv[8];
            if (IN_BF16) {
                short8 raw = *(const short8*)&Ab[(size_t)ar * D + kb];
                #pragma unroll
                for (int j = 0; j < 8; ++j)
                    vv[j] = __uint_as_float(((unsigned)(unsigned short)raw[j]) << 16);
            } else {
                const float* ap = &Af[(size_t)ar * D + kb];
                float4 v0 = *(const float4*)ap;
                float4 v1 = *(const float4*)(ap + 4);
                vv[0] = v0.x; vv[1] = v0.y; vv[2] = v0.z; vv[3] = v0.w;
                vv[4] = v1.x; vv[5] = v1.y; vv[6] = v1.z; vv[7] = v1.w;
            }
            short8 a8;
            #pragma unroll
            for (int j = 0; j < 8; ++j) {
                float f = vv[j];
                if (BN) f = fmaxf(fmaf(f, scs[kb + j], bis[kb + j]), 0.f);
                a8[j] = (short)f2bf(f);
            }
            af[ks] = a8;
        }

        f32x4 acc[8];
        #pragma unroll
        for (int ct = 0; ct < 8; ++ct) acc[ct] = (f32x4){0.f, 0.f, 0.f, 0.f};
        #pragma unroll
        for (int ks = 0; ks < 4; ++ks)
            #pragma unroll
            for (int ct = 0; ct < 8; ++ct)
                acc[ct] = __builtin_amdgcn_mfma_f32_16x16x32_bf16(af[ks], b[ct][ks], acc[ct], 0, 0, 0);

        // C/D layout: col = ct*16 + l15, row = t*16 + lg*4 + j
        const int rb2 = t * 16 + lg * 4;
        #pragma unroll
        for (int j = 0; j < 4; ++j) {
            const int row = rb2 + j;
            if (row < M) {
                #pragma unroll
                for (int ct = 0; ct < 8; ++ct) {
                    float o = acc[ct][j] + ob[ct];
                    if (OUT_BF16) Cb[(size_t)row * D + ct * 16 + l15] = f2bf(o);
                    else          C[(size_t)row * D + ct * 16 + l15] = o;
                    if (STATS) { psum[ct] += o; psq[ct] = fmaf(o, o, psq[ct]); }
                }
            }
        }
    }

    if (STATS) {
        #pragma unroll
        for (int ct = 0; ct < 8; ++ct) {
            atomicAdd(&ssum[ct * 16 + l15], psum[ct]);
            atomicAdd(&ssq[ct * 16 + l15], psq[ct]);
        }
        __syncthreads();
        const int rep = (blockIdx.x & (NREP - 1)) * D;
        if (tid < D) {
            unsafeAtomicAdd(&sum_out[rep + tid], ssum[tid]);
            unsafeAtomicAdd(&sq_out[rep + tid], ssq[tid]);
        }
    }
}

// bf16-pair load helper: word -> two floats
__device__ __forceinline__ void bfp(unsigned pv, float& fx, float& fy) {
    fx = __uint_as_float(pv << 16);
    fy = __uint_as_float(pv & 0xFFFF0000u);
}

// ---------------- gather over bf16 h2: TWO nodes per wave, 4-edge unroll, grid 1024 ----------------
// stats via replicated atomics (blockIdx&15)
__global__ __launch_bounds__(256) void gather_kernel(
    const int* __restrict__ ell, const int* __restrict__ cnt,
    const unsigned short* __restrict__ h2b,
    const float* __restrict__ b_conv, float* __restrict__ outpre,
    float* __restrict__ sum_out, float* __restrict__ sq_out)
{
    const int lane = threadIdx.x & 63;
    const int wid  = threadIdx.x >> 6;
    const int col  = lane * 2;
    const float2 bc = *(const float2*)&b_conv[col];
    float2 sum = make_float2(0.f, 0.f);
    float2 sq  = make_float2(0.f, 0.f);

    for (int d0 = blockIdx.x * 8 + wid * 2; d0 < N_NODES; d0 += gridDim.x * 8) {
        const int d1 = d0 + 1;
        int cAr = cnt[d0];
        int cBr = cnt[d1];
        const float ddA = rsqrtf((float)cAr + 1.0f);
        const float ddB = rsqrtf((float)cBr + 1.0f);
        int cA = cAr > ELLW ? ELLW : cAr;
        int cB = cBr > ELLW ? ELLW : cBr;
        float hAx, hAy, hBx, hBy;
        bfp(*(const unsigned*)&h2b[(size_t)d0 * D + col], hAx, hAy);
        bfp(*(const unsigned*)&h2b[(size_t)d1 * D + col], hBx, hBy);
        float2 accA, accB;
        accA.x = ddA * hAx; accA.y = ddA * hAy;
        accB.x = ddB * hBx; accB.y = ddB * hBy;

        int slA = 0, slB = 0;
        float wlA = 0.f, wlB = 0.f;
        if (lane < cA) { slA = ell[(size_t)d0 * ELLW + lane]; wlA = rsqrtf((float)cnt[slA] + 1.0f); }
        if (lane < cB) { slB = ell[(size_t)d1 * ELLW + lane]; wlB = rsqrtf((float)cnt[slB] + 1.0f); }

        const int cmin = cA < cB ? cA : cB;
        int j = 0;
        for (; j + 4 <= cmin; j += 4) {
            unsigned pA[4], pB[4];
            float wA[4], wB[4];
            #pragma unroll
            for (int u = 0; u < 4; ++u) {
                int sA = __shfl(slA, j + u);
                int sB = __shfl(slB, j + u);
                wA[u] = __shfl(wlA, j + u);
                wB[u] = __shfl(wlB, j + u);
                pA[u] = *(const unsigned*)&h2b[(size_t)sA * D + col];
                pB[u] = *(const unsigned*)&h2b[(size_t)sB * D + col];
            }
            #pragma unroll
            for (int u = 0; u < 4; ++u) {
                float ax, ay, bx, by;
                bfp(pA[u], ax, ay);
                bfp(pB[u], bx, by);
                accA.x = fmaf(wA[u], ax, accA.x);
                accA.y = fmaf(wA[u], ay, accA.y);
                accB.x = fmaf(wB[u], bx, accB.x);
                accB.y = fmaf(wB[u], by, accB.y);
            }
        }
        int jA = j, jB = j;
        for (; jA < cA; ++jA) {
            int s = __shfl(slA, jA);
            float ww = __shfl(wlA, jA);
            float ax, ay;
            bfp(*(const unsigned*)&h2b[(size_t)s * D + col], ax, ay);
            accA.x = fmaf(ww, ax, accA.x);
            accA.y = fmaf(ww, ay, accA.y);
        }
        for (; jB < cB; ++jB) {
            int s = __shfl(slB, jB);
            float ww = __shfl(wlB, jB);
            float bx, by;
            bfp(*(const unsigned*)&h2b[(size_t)s * D + col], bx, by);
            accB.x = fmaf(ww, bx, accB.x);
            accB.y = fmaf(ww, by, accB.y);
        }

        float2 oA, oB;
        oA.x = fmaf(ddA, accA.x, bc.x);
        oA.y = fmaf(ddA, accA.y, bc.y);
        oB.x = fmaf(ddB, accB.x, bc.x);
        oB.y = fmaf(ddB, accB.y, bc.y);
        *(float2*)&outpre[(size_t)d0 * D + col] = oA;
        *(float2*)&outpre[(size_t)d1 * D + col] = oB;
        sum.x += oA.x + oB.x; sum.y += oA.y + oB.y;
        sq.x = fmaf(oA.x, oA.x, sq.x); sq.x = fmaf(oB.x, oB.x, sq.x);
        sq.y = fmaf(oA.y, oA.y, sq.y); sq.y = fmaf(oB.y, oB.y, sq.y);
    }

    __shared__ float2 sS[256];
    __shared__ float2 qS[256];
    sS[threadIdx.x] = sum; qS[threadIdx.x] = sq;
    __syncthreads();
    if (wid == 0) {
        #pragma unroll
        for (int w = 1; w < 4; ++w) {
            float2 s2 = sS[w * 64 + lane];
            float2 q2 = qS[w * 64 + lane];
            sum.x += s2.x; sum.y += s2.y;
            sq.x += q2.x; sq.y += q2.y;
        }
        const int rep = (blockIdx.x & (NREP - 1)) * D;
        unsafeAtomicAdd(&sum_out[rep + col + 0], sum.x);
        unsafeAtomicAdd(&sum_out[rep + col + 1], sum.y);
        unsafeAtomicAdd(&sq_out[rep + col + 0], sq.x);
        unsafeAtomicAdd(&sq_out[rep + col + 1], sq.y);
    }
}

// ---------------- final: out = relu(out*scale2 + bias2), scale/bias from replicated stats ----------------
__global__ void final_kernel(float* __restrict__ out,
        const float* __restrict__ s_sum, const float* __restrict__ s_sq,
        const float* __restrict__ gamma, const float* __restrict__ beta) {
    __shared__ __align__(16) float scs[D];
    __shared__ __align__(16) float bis[D];
    const int tid = threadIdx.x;
    if (tid < D) {
        float s = 0.f, q = 0.f;
        #pragma unroll
        for (int r = 0; r < NREP; ++r) { s += s_sum[r * D + tid]; q += s_sq[r * D + tid]; }
        const float inv_n = 1.0f / (float)N_NODES;
        float mean = s * inv_n;
        float var  = q * inv_n - mean * mean;
        float rstd = rsqrtf(var + BN_EPS);
        float sc = gamma[tid] * rstd;
        scs[tid] = sc;
        bis[tid] = beta[tid] - mean * sc;
    }
    __syncthreads();
    const int t = blockIdx.x * blockDim.x + tid;
    const int c4 = t & 31;
    float4 sc = *(const float4*)&scs[c4 * 4];
    float4 bi = *(const float4*)&bis[c4 * 4];
    const int total = N_NODES * D / 4;
    const int stride = gridDim.x * blockDim.x;
    for (int i = t; i < total; i += stride) {
        float4 v = ((const float4*)out)[i];
        v.x = fmaxf(fmaf(v.x, sc.x, bi.x), 0.f);
        v.y = fmaxf(fmaf(v.y, sc.y, bi.y), 0.f);
        v.z = fmaxf(fmaf(v.z, sc.z, bi.z), 0.f);
        v.w = fmaxf(fmaf(v.w, sc.w, bi.w), 0.f);
        ((float4*)out)[i] = v;
    }
}

extern "C" void kernel_launch(void* const* d_in, const int* in_sizes, int n_in,
                              void* d_out, int out_size, void* d_ws, size_t ws_size,
                              hipStream_t stream) {
    const float* x      = (const float*)d_in[0];
    const int*   edge   = (const int*)d_in[1];      // [2][N_EDGES], row0=src, row1=dst
    const float* W_mlp  = (const float*)d_in[2];
    const float* b_mlp  = (const float*)d_in[3];
    const float* gamma1 = (const float*)d_in[4];
    const float* beta1  = (const float*)d_in[5];
    const float* W_conv = (const float*)d_in[6];
    const float* b_conv = (const float*)d_in[7];
    const float* gamma2 = (const float*)d_in[8];
    const float* beta2  = (const float*)d_in[9];
    float* out = (float*)d_out;

    float* ws = (float*)d_ws;
    unsigned short* h1b = (unsigned short*)ws;                             // N*D bf16 (12.8 MB)
    unsigned short* h2b = (unsigned short*)(ws + (size_t)N_NODES * D / 2); // N*D bf16 (12.8 MB)
    int*   ell  = (int*)h1b;                           // alias: h1b dead after gemm2 (12.8MB exact)
    float* extra = ws + (size_t)N_NODES * D;           // beyond h1b+h2b
    int*   cur  = (int*)extra;                         // N ints (ELL cursors / in-degree)
    float* stats = extra + N_NODES;                    // NREP*4*D floats (32 KB)
    float* sum1 = stats;                  float* sq1 = stats + NREP * D;
    float* sum2 = stats + 2 * NREP * D;   float* sq2 = stats + 3 * NREP * D;
    unsigned short* WT1 = (unsigned short*)(stats + 4 * NREP * D);   // 128*128 bf16
    unsigned short* WT2 = WT1 + D * D;

    const int* srcI = edge;
    const int* dstI = edge + N_EDGES;

    prep_kernel<<<(N_NODES + 255) / 256, 256, 0, stream>>>(W_mlp, W_conv, WT1, WT2, cur, stats);

    gemm_ws_kernel<false, true, true, false, true><<<392, 256, 0, stream>>>(
        x, nullptr, WT1, nullptr, nullptr, nullptr, nullptr, b_mlp, nullptr, h1b, N_NODES, sum1, sq1);

    gemm_ws_kernel<true, false, false, true, true><<<392, 256, 0, stream>>>(
        nullptr, h1b, WT2, sum1, sq1, gamma1, beta1, nullptr, nullptr, h2b, N_NODES, nullptr, nullptr);

    // h1b is dead now: build src ELL in its place
    scatter_kernel<<<(N_EDGES + 255) / 256, 256, 0, stream>>>(srcI, dstI, cur, ell);

    gather_kernel<<<1024, 256, 0, stream>>>(ell, cur, h2b, b_conv, out, sum2, sq2);

    final_kernel<<<2048, 256, 0, stream>>>(out, sum2, sq2, gamma2, beta2);
}

// Round 15
// 192.111 us; speedup vs baseline: 1.7060x; 1.1118x over previous
//
#include <hip/hip_runtime.h>
#include <math.h>

#define N_NODES 50000
#define N_EDGES 600000
#define D 128
#define BN_EPS 1e-5f
#define ELLW 64
#define NREP 16          // stats replica count (atomic-contention spreading)
#define GEMM1_BLOCKS 392 // gemm part of the fused gemm1+scatter dispatch

typedef float f32x4 __attribute__((ext_vector_type(4)));
typedef short short8 __attribute__((ext_vector_type(8)));

__device__ __forceinline__ unsigned short f2bf(float f) {
    unsigned int x = __float_as_uint(f);
    return (unsigned short)((x + 0x7FFFu + ((x >> 16) & 1u)) >> 16);  // RNE
}

// ---------------- prep: transpose+bf16 weights, zero cur + replicated stats ----------------
__global__ void prep_kernel(const float* __restrict__ W1, const float* __restrict__ W2,
                            unsigned short* __restrict__ WT1, unsigned short* __restrict__ WT2,
                            int* __restrict__ cur, float* __restrict__ stats) {
    int idx = blockIdx.x * blockDim.x + threadIdx.x;
    if (idx < D * D) {
        int col = idx >> 7, k = idx & 127;
        WT1[col * D + k] = f2bf(W1[k * D + col]);
        WT2[col * D + k] = f2bf(W2[k * D + col]);
    }
    if (idx < N_NODES) cur[idx] = 0;
    if (idx < NREP * 4 * D) stats[idx] = 0.0f;
}

// ---------------- FUSED: gemm1 (blocks < GEMM1_BLOCKS) + edge scatter (rest) ----------------
// gemm1: h1b = bf16(x @ WT1^T + b_mlp), fused replicated col stats.
// scatter: ELL build - independent of gemm1 (ell does NOT alias h1b anymore).
__global__ __launch_bounds__(256, 2) void gemm1_scatter_kernel(
    const float* __restrict__ A, const unsigned short* __restrict__ WT,
    const float* __restrict__ out_bias, unsigned short* __restrict__ Cb, int M,
    float* __restrict__ sum_out, float* __restrict__ sq_out,
    const int* __restrict__ srcI, const int* __restrict__ dstI,
    int* __restrict__ cur, int* __restrict__ ell)
{
    const int tid = threadIdx.x;

    if (blockIdx.x >= GEMM1_BLOCKS) {
        // ---- scatter role ----
        int e = (blockIdx.x - GEMM1_BLOCKS) * 256 + tid;
        if (e < N_EDGES) {
            int d = dstI[e];
            int pos = atomicAdd(&cur[d], 1);
            if (pos < ELLW) ell[(size_t)d * ELLW + pos] = srcI[e];
        }
        return;
    }

    // ---- gemm1 role (weight-stationary, R10/R14-proven) ----
    __shared__ float ssum[D];
    __shared__ float ssq[D];

    const int lane = tid & 63;
    const int w    = tid >> 6;
    const int l15  = lane & 15;
    const int lg   = lane >> 4;

    if (tid < D) { ssum[tid] = 0.f; ssq[tid] = 0.f; }
    __syncthreads();

    short8 b[8][4];
    #pragma unroll
    for (int ct = 0; ct < 8; ++ct)
        #pragma unroll
        for (int ks = 0; ks < 4; ++ks)
            b[ct][ks] = *(const short8*)&WT[(size_t)(ct * 16 + l15) * D + ks * 32 + lg * 8];

    float ob[8];
    #pragma unroll
    for (int ct = 0; ct < 8; ++ct) ob[ct] = out_bias[ct * 16 + l15];

    float psum[8], psq[8];
    #pragma unroll
    for (int ct = 0; ct < 8; ++ct) { psum[ct] = 0.f; psq[ct] = 0.f; }

    const int nt = (M + 15) / 16;
    for (int t = blockIdx.x * 4 + w; t < nt; t += GEMM1_BLOCKS * 4) {
        int ar = t * 16 + l15; if (ar > M - 1) ar = M - 1;
        short8 af[4];
        #pragma unroll
        for (int ks = 0; ks < 4; ++ks) {
            const int kb = ks * 32 + lg * 8;
            const float* ap = &A[(size_t)ar * D + kb];
            float4 v0 = *(const float4*)ap;
            float4 v1 = *(const float4*)(ap + 4);
            float vv[8] = {v0.x, v0.y, v0.z, v0.w, v1.x, v1.y, v1.z, v1.w};
            short8 a8;
            #pragma unroll
            for (int j = 0; j < 8; ++j) a8[j] = (short)f2bf(vv[j]);
            af[ks] = a8;
        }

        f32x4 acc[8];
        #pragma unroll
        for (int ct = 0; ct < 8; ++ct) acc[ct] = (f32x4){0.f, 0.f, 0.f, 0.f};
        #pragma unroll
        for (int ks = 0; ks < 4; ++ks)
            #pragma unroll
            for (int ct = 0; ct < 8; ++ct)
                acc[ct] = __builtin_amdgcn_mfma_f32_16x16x32_bf16(af[ks], b[ct][ks], acc[ct], 0, 0, 0);

        const int rb2 = t * 16 + lg * 4;
        #pragma unroll
        for (int j = 0; j < 4; ++j) {
            const int row = rb2 + j;
            if (row < M) {
                #pragma unroll
                for (int ct = 0; ct < 8; ++ct) {
                    float o = acc[ct][j] + ob[ct];
                    Cb[(size_t)row * D + ct * 16 + l15] = f2bf(o);
                    psum[ct] += o; psq[ct] = fmaf(o, o, psq[ct]);
                }
            }
        }
    }

    #pragma unroll
    for (int ct = 0; ct < 8; ++ct) {
        atomicAdd(&ssum[ct * 16 + l15], psum[ct]);
        atomicAdd(&ssq[ct * 16 + l15], psq[ct]);
    }
    __syncthreads();
    const int rep = (blockIdx.x & (NREP - 1)) * D;
    if (tid < D) {
        unsafeAtomicAdd(&sum_out[rep + tid], ssum[tid]);
        unsafeAtomicAdd(&sq_out[rep + tid], ssq[tid]);
    }
}

// ---------------- gemm2: weight-stationary, BN1+ReLU on bf16 input, bf16 out ----------------
__global__ __launch_bounds__(256, 2) void gemm2_kernel(
    const unsigned short* __restrict__ Ab, const unsigned short* __restrict__ WT,
    const float* __restrict__ bn_sum, const float* __restrict__ bn_sq,
    const float* __restrict__ bn_gamma, const float* __restrict__ bn_beta,
    unsigned short* __restrict__ Cb, int M)
{
    __shared__ __align__(16) float scs[D];
    __shared__ __align__(16) float bis[D];

    const int tid  = threadIdx.x;
    const int lane = tid & 63;
    const int w    = tid >> 6;
    const int l15  = lane & 15;
    const int lg   = lane >> 4;

    if (tid < D) {
        float s = 0.f, q = 0.f;
        #pragma unroll
        for (int r = 0; r < NREP; ++r) { s += bn_sum[r * D + tid]; q += bn_sq[r * D + tid]; }
        const float inv_n = 1.0f / (float)N_NODES;
        float mean = s * inv_n;
        float var  = q * inv_n - mean * mean;
        float rstd = rsqrtf(var + BN_EPS);
        float sc = bn_gamma[tid] * rstd;
        scs[tid] = sc;
        bis[tid] = bn_beta[tid] - mean * sc;
    }
    __syncthreads();

    short8 b[8][4];
    #pragma unroll
    for (int ct = 0; ct < 8; ++ct)
        #pragma unroll
        for (int ks = 0; ks < 4; ++ks)
            b[ct][ks] = *(const short8*)&WT[(size_t)(ct * 16 + l15) * D + ks * 32 + lg * 8];

    const int nt = (M + 15) / 16;
    for (int t = blockIdx.x * 4 + w; t < nt; t += gridDim.x * 4) {
        int ar = t * 16 + l15; if (ar > M - 1) ar = M - 1;
        short8 af[4];
        #pragma unroll
        for (int ks = 0; ks < 4; ++ks) {
            const int kb = ks * 32 + lg * 8;
            short8 raw = *(const short8*)&Ab[(size_t)ar * D + kb];
            short8 a8;
            #pragma unroll
            for (int j = 0; j < 8; ++j) {
                float f = __uint_as_float(((unsigned)(unsigned short)raw[j]) << 16);
                f = fmaxf(fmaf(f, scs[kb + j], bis[kb + j]), 0.f);
                a8[j] = (short)f2bf(f);
            }
            af[ks] = a8;
        }

        f32x4 acc[8];
        #pragma unroll
        for (int ct = 0; ct < 8; ++ct) acc[ct] = (f32x4){0.f, 0.f, 0.f, 0.f};
        #pragma unroll
        for (int ks = 0; ks < 4; ++ks)
            #pragma unroll
            for (int ct = 0; ct < 8; ++ct)
                acc[ct] = __builtin_amdgcn_mfma_f32_16x16x32_bf16(af[ks], b[ct][ks], acc[ct], 0, 0, 0);

        const int rb2 = t * 16 + lg * 4;
        #pragma unroll
        for (int j = 0; j < 4; ++j) {
            const int row = rb2 + j;
            if (row < M) {
                #pragma unroll
                for (int ct = 0; ct < 8; ++ct)
                    Cb[(size_t)row * D + ct * 16 + l15] = f2bf(acc[ct][j]);
            }
        }
    }
}

// bf16-pair load helper: word -> two floats
__device__ __forceinline__ void bfp(unsigned pv, float& fx, float& fy) {
    fx = __uint_as_float(pv << 16);
    fy = __uint_as_float(pv & 0xFFFF0000u);
}

// ---------------- gather over bf16 h2: TWO nodes per wave, 4-edge unroll ----------------
// stats via replicated atomics (blockIdx&15); grid 2048 (re-test with replication)
__global__ __launch_bounds__(256) void gather_kernel(
    const int* __restrict__ ell, const int* __restrict__ cnt,
    const unsigned short* __restrict__ h2b,
    const float* __restrict__ b_conv, float* __restrict__ outpre,
    float* __restrict__ sum_out, float* __restrict__ sq_out)
{
    const int lane = threadIdx.x & 63;
    const int wid  = threadIdx.x >> 6;
    const int col  = lane * 2;
    const float2 bc = *(const float2*)&b_conv[col];
    float2 sum = make_float2(0.f, 0.f);
    float2 sq  = make_float2(0.f, 0.f);

    for (int d0 = blockIdx.x * 8 + wid * 2; d0 < N_NODES; d0 += gridDim.x * 8) {
        const int d1 = d0 + 1;
        int cAr = cnt[d0];
        int cBr = cnt[d1];
        const float ddA = rsqrtf((float)cAr + 1.0f);
        const float ddB = rsqrtf((float)cBr + 1.0f);
        int cA = cAr > ELLW ? ELLW : cAr;
        int cB = cBr > ELLW ? ELLW : cBr;
        float hAx, hAy, hBx, hBy;
        bfp(*(const unsigned*)&h2b[(size_t)d0 * D + col], hAx, hAy);
        bfp(*(const unsigned*)&h2b[(size_t)d1 * D + col], hBx, hBy);
        float2 accA, accB;
        accA.x = ddA * hAx; accA.y = ddA * hAy;
        accB.x = ddB * hBx; accB.y = ddB * hBy;

        int slA = 0, slB = 0;
        float wlA = 0.f, wlB = 0.f;
        if (lane < cA) { slA = ell[(size_t)d0 * ELLW + lane]; wlA = rsqrtf((float)cnt[slA] + 1.0f); }
        if (lane < cB) { slB = ell[(size_t)d1 * ELLW + lane]; wlB = rsqrtf((float)cnt[slB] + 1.0f); }

        const int cmin = cA < cB ? cA : cB;
        int j = 0;
        for (; j + 4 <= cmin; j += 4) {
            unsigned pA[4], pB[4];
            float wA[4], wB[4];
            #pragma unroll
            for (int u = 0; u < 4; ++u) {
                int sA = __shfl(slA, j + u);
                int sB = __shfl(slB, j + u);
                wA[u] = __shfl(wlA, j + u);
                wB[u] = __shfl(wlB, j + u);
                pA[u] = *(const unsigned*)&h2b[(size_t)sA * D + col];
                pB[u] = *(const unsigned*)&h2b[(size_t)sB * D + col];
            }
            #pragma unroll
            for (int u = 0; u < 4; ++u) {
                float ax, ay, bx, by;
                bfp(pA[u], ax, ay);
                bfp(pB[u], bx, by);
                accA.x = fmaf(wA[u], ax, accA.x);
                accA.y = fmaf(wA[u], ay, accA.y);
                accB.x = fmaf(wB[u], bx, accB.x);
                accB.y = fmaf(wB[u], by, accB.y);
            }
        }
        int jA = j, jB = j;
        for (; jA < cA; ++jA) {
            int s = __shfl(slA, jA);
            float ww = __shfl(wlA, jA);
            float ax, ay;
            bfp(*(const unsigned*)&h2b[(size_t)s * D + col], ax, ay);
            accA.x = fmaf(ww, ax, accA.x);
            accA.y = fmaf(ww, ay, accA.y);
        }
        for (; jB < cB; ++jB) {
            int s = __shfl(slB, jB);
            float ww = __shfl(wlB, jB);
            float bx, by;
            bfp(*(const unsigned*)&h2b[(size_t)s * D + col], bx, by);
            accB.x = fmaf(ww, bx, accB.x);
            accB.y = fmaf(ww, by, accB.y);
        }

        float2 oA, oB;
        oA.x = fmaf(ddA, accA.x, bc.x);
        oA.y = fmaf(ddA, accA.y, bc.y);
        oB.x = fmaf(ddB, accB.x, bc.x);
        oB.y = fmaf(ddB, accB.y, bc.y);
        *(float2*)&outpre[(size_t)d0 * D + col] = oA;
        *(float2*)&outpre[(size_t)d1 * D + col] = oB;
        sum.x += oA.x + oB.x; sum.y += oA.y + oB.y;
        sq.x = fmaf(oA.x, oA.x, sq.x); sq.x = fmaf(oB.x, oB.x, sq.x);
        sq.y = fmaf(oA.y, oA.y, sq.y); sq.y = fmaf(oB.y, oB.y, sq.y);
    }

    __shared__ float2 sS[256];
    __shared__ float2 qS[256];
    sS[threadIdx.x] = sum; qS[threadIdx.x] = sq;
    __syncthreads();
    if (wid == 0) {
        #pragma unroll
        for (int w = 1; w < 4; ++w) {
            float2 s2 = sS[w * 64 + lane];
            float2 q2 = qS[w * 64 + lane];
            sum.x += s2.x; sum.y += s2.y;
            sq.x += q2.x; sq.y += q2.y;
        }
        const int rep = (blockIdx.x & (NREP - 1)) * D;
        unsafeAtomicAdd(&sum_out[rep + col + 0], sum.x);
        unsafeAtomicAdd(&sum_out[rep + col + 1], sum.y);
        unsafeAtomicAdd(&sq_out[rep + col + 0], sq.x);
        unsafeAtomicAdd(&sq_out[rep + col + 1], sq.y);
    }
}

// ---------------- final: out = relu(out*scale2 + bias2), scale/bias from replicated stats ----------------
__global__ void final_kernel(float* __restrict__ out,
        const float* __restrict__ s_sum, const float* __restrict__ s_sq,
        const float* __restrict__ gamma, const float* __restrict__ beta) {
    __shared__ __align__(16) float scs[D];
    __shared__ __align__(16) float bis[D];
    const int tid = threadIdx.x;
    if (tid < D) {
        float s = 0.f, q = 0.f;
        #pragma unroll
        for (int r = 0; r < NREP; ++r) { s += s_sum[r * D + tid]; q += s_sq[r * D + tid]; }
        const float inv_n = 1.0f / (float)N_NODES;
        float mean = s * inv_n;
        float var  = q * inv_n - mean * mean;
        float rstd = rsqrtf(var + BN_EPS);
        float sc = gamma[tid] * rstd;
        scs[tid] = sc;
        bis[tid] = beta[tid] - mean * sc;
    }
    __syncthreads();
    const int t = blockIdx.x * blockDim.x + tid;
    const int c4 = t & 31;
    float4 sc = *(const float4*)&scs[c4 * 4];
    float4 bi = *(const float4*)&bis[c4 * 4];
    const int total = N_NODES * D / 4;
    const int stride = gridDim.x * blockDim.x;
    for (int i = t; i < total; i += stride) {
        float4 v = ((const float4*)out)[i];
        v.x = fmaxf(fmaf(v.x, sc.x, bi.x), 0.f);
        v.y = fmaxf(fmaf(v.y, sc.y, bi.y), 0.f);
        v.z = fmaxf(fmaf(v.z, sc.z, bi.z), 0.f);
        v.w = fmaxf(fmaf(v.w, sc.w, bi.w), 0.f);
        ((float4*)out)[i] = v;
    }
}

extern "C" void kernel_launch(void* const* d_in, const int* in_sizes, int n_in,
                              void* d_out, int out_size, void* d_ws, size_t ws_size,
                              hipStream_t stream) {
    const float* x      = (const float*)d_in[0];
    const int*   edge   = (const int*)d_in[1];      // [2][N_EDGES], row0=src, row1=dst
    const float* W_mlp  = (const float*)d_in[2];
    const float* b_mlp  = (const float*)d_in[3];
    const float* gamma1 = (const float*)d_in[4];
    const float* beta1  = (const float*)d_in[5];
    const float* W_conv = (const float*)d_in[6];
    const float* b_conv = (const float*)d_in[7];
    const float* gamma2 = (const float*)d_in[8];
    const float* beta2  = (const float*)d_in[9];
    float* out = (float*)d_out;

    // layout (no aliasing): h1b | h2b | ell | cur | stats | WT1 | WT2  ~= 38.7 MB
    unsigned short* h1b = (unsigned short*)d_ws;                 // N*D bf16 (12.8 MB)
    unsigned short* h2b = h1b + (size_t)N_NODES * D;             // N*D bf16 (12.8 MB)
    int*   ell  = (int*)(h2b + (size_t)N_NODES * D);             // N*ELLW ints (12.8 MB)
    int*   cur  = ell + (size_t)N_NODES * ELLW;                  // N ints
    float* stats = (float*)(cur + N_NODES);                      // NREP*4*D floats
    float* sum1 = stats;                  float* sq1 = stats + NREP * D;
    float* sum2 = stats + 2 * NREP * D;   float* sq2 = stats + 3 * NREP * D;
    unsigned short* WT1 = (unsigned short*)(stats + 4 * NREP * D);   // 128*128 bf16
    unsigned short* WT2 = WT1 + D * D;

    const int* srcI = edge;
    const int* dstI = edge + N_EDGES;

    prep_kernel<<<(N_NODES + 255) / 256, 256, 0, stream>>>(W_mlp, W_conv, WT1, WT2, cur, stats);

    const int scatter_blocks = (N_EDGES + 255) / 256;   // 2344
    gemm1_scatter_kernel<<<GEMM1_BLOCKS + scatter_blocks, 256, 0, stream>>>(
        x, WT1, b_mlp, h1b, N_NODES, sum1, sq1, srcI, dstI, cur, ell);

    gemm2_kernel<<<392, 256, 0, stream>>>(
        h1b, WT2, sum1, sq1, gamma1, beta1, h2b, N_NODES);

    gather_kernel<<<2048, 256, 0, stream>>>(ell, cur, h2b, b_conv, out, sum2, sq2);

    final_kernel<<<2048, 256, 0, stream>>>(out, sum2, sq2, gamma2, beta2);
}